// Round 3
// baseline (1144.003 us; speedup 1.0000x reference)
//
#include <hip/hip_runtime.h>
#include <stdint.h>

#define NQ 12
#define NL 5
#define AMPS 16   // amplitudes per lane

// One 256-thread block (4 waves) per batch element. Amp index:
//   idx = (wv << 10) | (lane << 4) | r      (wv = wave 0..3, r = 0..15)
// Wire w <-> idx bit (11-w):
//   wires 0,1   -> wv bits 1,0   -> LDS exchange between wave pairs
//   wires 2..7  -> lane bits 5..0 -> cross-lane xor 32,16,8,4,2,1
//   wires 8..11 -> r bits 3..0   -> in-register pair butterfly
// Small code body (~15 KB) stays L1I-resident; 16 waves/CU hide latency.

static __device__ __forceinline__ float f_u(unsigned u) { return __uint_as_float(u); }
static __device__ __forceinline__ unsigned u_f(float f) { return __float_as_uint(f); }

template <int CTRL>
static __device__ __forceinline__ float dpp_xor(float v) {
    int u = (int)__float_as_uint(v);
    return __uint_as_float((unsigned)__builtin_amdgcn_update_dpp(u, u, CTRL, 0xF, 0xF, false));
}
static __device__ __forceinline__ float swz_xor4(float v) {
    return f_u((unsigned)__builtin_amdgcn_ds_swizzle((int)u_f(v), 0x101F));
}

#define COEF(Q)                                                         \
    const float ar_ = f_u(__builtin_amdgcn_readlane(u_f(ar), (Q)));     \
    const float ai_ = f_u(__builtin_amdgcn_readlane(u_f(ai), (Q)));     \
    const float br_ = f_u(__builtin_amdgcn_readlane(u_f(br), (Q)));     \
    const float bi_ = f_u(__builtin_amdgcn_readlane(u_f(bi), (Q)));

// A/B form for wires where we fetch partner value o: out = A*s + B*o
#define AB_COEF(BIT)                                                    \
    const int   bit = (BIT);                                            \
    const float Ar = ar_;                                               \
    const float Ai = bit ? -ai_ : ai_;                                  \
    const float Br = bit ? -br_ : br_;                                  \
    const float Bi = bi_;

#define AB_GATE(OP)                                                     \
    _Pragma("unroll")                                                   \
    for (int r = 0; r < AMPS; ++r) {                                    \
        const float s_r = sr[r], s_i = si[r];                           \
        const float o_r = OP(s_r);                                      \
        const float o_i = OP(s_i);                                      \
        sr[r] = Ar * s_r - Ai * s_i + Br * o_r - Bi * o_i;              \
        si[r] = Ar * s_i + Ai * s_r + Br * o_i + Bi * o_r;              \
    }

// permlane-swap form: swap(v,v) -> {lo-half replicated, hi-half replicated};
// out = P*na + Q*nb, P/Q per-lane coefs (no per-amp select).
#define PQ_COEF(HB)                                                     \
    const int   hb = (HB);                                              \
    const float Pr = hb ? -br_ : ar_;                                   \
    const float Pi = hb ?  bi_ : ai_;                                   \
    const float Qr = hb ?  ar_ : br_;                                   \
    const float Qi = hb ? -ai_ : bi_;

#define PQ_GATE(SWAP)                                                   \
    _Pragma("unroll")                                                   \
    for (int r = 0; r < AMPS; ++r) {                                    \
        auto dr_ = SWAP(u_f(sr[r]), u_f(sr[r]), false, false);          \
        auto di_ = SWAP(u_f(si[r]), u_f(si[r]), false, false);          \
        const float nar = f_u(dr_[0]), nbr = f_u(dr_[1]);               \
        const float nai = f_u(di_[0]), nbi = f_u(di_[1]);               \
        sr[r] = Pr * nar - Pi * nai + Qr * nbr - Qi * nbi;              \
        si[r] = Pr * nai + Pi * nar + Qr * nbi + Qi * nbr;              \
    }

template <int ST>
static __device__ __forceinline__ void reg_gate(float (&sr)[AMPS], float (&si)[AMPS],
                                                float ar, float ai, float br, float bi) {
#pragma unroll
    for (int r0 = 0; r0 < AMPS; ++r0) {
        if (r0 & ST) continue;
        const int r1 = r0 | ST;
        const float s0r = sr[r0], s0i = si[r0];
        const float s1r = sr[r1], s1i = si[r1];
        sr[r0] =  ar * s0r - ai * s0i + br * s1r - bi * s1i;
        si[r0] =  ar * s0i + ai * s0r + br * s1i + bi * s1r;
        sr[r1] = -br * s0r - bi * s0i + ar * s1r + ai * s1i;
        si[r1] = -br * s0i + bi * s0r + ar * s1i - ai * s1r;
    }
}

__global__ __launch_bounds__(256, 4) void qsim_kernel(
    const float* __restrict__ x,
    const float* __restrict__ iscale,
    const float* __restrict__ w,
    const float* __restrict__ oscale,
    float* __restrict__ out,
    int batch)
{
    const int tid  = threadIdx.x;
    const int lane = tid & 63;
    const int wv   = tid >> 6;
    const int b    = blockIdx.x;
    if (b >= batch) return;

    __shared__ float4 xch[8 * 256];   // [k:8][tid:256], 32 KB, conflict-free

    float sr[AMPS], si[AMPS];
#pragma unroll
    for (int r = 0; r < AMPS; ++r) { sr[r] = 0.f; si[r] = 0.f; }
    if (tid == 0) sr[0] = 1.f;

    // CZ-ring sign bits (16 per lane)
    unsigned czm = 0;
#pragma unroll
    for (int r = 0; r < AMPS; ++r) {
        unsigned idx  = ((unsigned)wv << 10) | ((unsigned)lane << 4) | (unsigned)r;
        unsigned adj  = (idx & (idx >> 1)) & 0x7FFu;
        unsigned wrap = (idx & (idx >> 11)) & 1u;
        czm |= (((unsigned)__popc(adj) + wrap) & 1u) << r;
    }

    const int ql = (lane < NQ) ? lane : 0;
    const float* xb = x + (size_t)b * (4 * NQ);

#pragma unroll 1
    for (int it = 0; it < NL * 3; ++it) {
        const int blk = it - 3 * (it / 3);

        // fused U = RZ*RY*RX for qubit ql (built by lanes 0..11)
        float f     = xb[NQ + blk * NQ + ql];
        float alpha = iscale[it * NQ + ql] * f;
        float beta  = w[it * 2 * NQ + ql];
        float gamma = w[it * 2 * NQ + NQ + ql];
        float sa, ca, sb, cb, sg, cg;
        sincosf(0.5f * alpha, &sa, &ca);
        sincosf(0.5f * beta,  &sb, &cb);
        sincosf(0.5f * gamma, &sg, &cg);
        float cbca = cb * ca, sbsa = sb * sa, sbca = sb * ca, cbsa = cb * sa;
        float ar =  cg * cbca + sg * sbsa;
        float ai =  cg * sbsa - sg * cbca;
        float br = -(cg * sbca + sg * cbsa);
        float bi =  sg * sbca - cg * cbsa;

        // ---- wave wires (qubits 0,1): LDS exchange ----
        {
            COEF(0); AB_COEF((wv >> 1) & 1);
            __syncthreads();   // prior LDS readers done
#pragma unroll
            for (int k = 0; k < 8; ++k)
                xch[(k << 8) + tid] = make_float4(sr[2*k], si[2*k], sr[2*k+1], si[2*k+1]);
            __syncthreads();
            const int ptid = tid ^ (2 << 6);
#pragma unroll
            for (int k = 0; k < 8; ++k) {
                float4 o = xch[(k << 8) + ptid];
                float s0r = sr[2*k], s0i = si[2*k];
                sr[2*k]   = Ar*s0r - Ai*s0i + Br*o.x - Bi*o.y;
                si[2*k]   = Ar*s0i + Ai*s0r + Br*o.y + Bi*o.x;
                float s1r = sr[2*k+1], s1i = si[2*k+1];
                sr[2*k+1] = Ar*s1r - Ai*s1i + Br*o.z - Bi*o.w;
                si[2*k+1] = Ar*s1i + Ai*s1r + Br*o.w + Bi*o.z;
            }
        }
        {
            COEF(1); AB_COEF(wv & 1);
            __syncthreads();
#pragma unroll
            for (int k = 0; k < 8; ++k)
                xch[(k << 8) + tid] = make_float4(sr[2*k], si[2*k], sr[2*k+1], si[2*k+1]);
            __syncthreads();
            const int ptid = tid ^ (1 << 6);
#pragma unroll
            for (int k = 0; k < 8; ++k) {
                float4 o = xch[(k << 8) + ptid];
                float s0r = sr[2*k], s0i = si[2*k];
                sr[2*k]   = Ar*s0r - Ai*s0i + Br*o.x - Bi*o.y;
                si[2*k]   = Ar*s0i + Ai*s0r + Br*o.y + Bi*o.x;
                float s1r = sr[2*k+1], s1i = si[2*k+1];
                sr[2*k+1] = Ar*s1r - Ai*s1i + Br*o.z - Bi*o.w;
                si[2*k+1] = Ar*s1i + Ai*s1r + Br*o.w + Bi*o.z;
            }
        }

        // ---- lane wires (qubits 2..7) ----
        { // qubit 2: xor32
            COEF(2);
#if __has_builtin(__builtin_amdgcn_permlane32_swap)
            PQ_COEF((lane >> 5) & 1);
            PQ_GATE(__builtin_amdgcn_permlane32_swap)
#else
            AB_COEF((lane >> 5) & 1);
#define X32(v) __shfl_xor((v), 32)
            AB_GATE(X32)
#undef X32
#endif
        }
        { // qubit 3: xor16
            COEF(3);
#if __has_builtin(__builtin_amdgcn_permlane16_swap)
            PQ_COEF((lane >> 4) & 1);
            PQ_GATE(__builtin_amdgcn_permlane16_swap)
#else
            AB_COEF((lane >> 4) & 1);
#define X16(v) __shfl_xor((v), 16)
            AB_GATE(X16)
#undef X16
#endif
        }
        { // qubit 4: xor8 -> DPP row_ror:8
            COEF(4); AB_COEF((lane >> 3) & 1);
            AB_GATE(dpp_xor<0x128>)
        }
        { // qubit 5: xor4 -> ds_swizzle
            COEF(5); AB_COEF((lane >> 2) & 1);
            AB_GATE(swz_xor4)
        }
        { // qubit 6: xor2 -> DPP quad_perm [2,3,0,1]
            COEF(6); AB_COEF((lane >> 1) & 1);
            AB_GATE(dpp_xor<0x4E>)
        }
        { // qubit 7: xor1 -> DPP quad_perm [1,0,3,2]
            COEF(7); AB_COEF(lane & 1);
            AB_GATE(dpp_xor<0xB1>)
        }

        // ---- register wires (qubits 8..11) ----
        { COEF(8);  reg_gate<8>(sr, si, ar_, ai_, br_, bi_); }
        { COEF(9);  reg_gate<4>(sr, si, ar_, ai_, br_, bi_); }
        { COEF(10); reg_gate<2>(sr, si, ar_, ai_, br_, bi_); }
        { COEF(11); reg_gate<1>(sr, si, ar_, ai_, br_, bi_); }

        // ---- CZ ring (diagonal +-1) ----
#pragma unroll
        for (int r = 0; r < AMPS; ++r) {
            const unsigned sgn = ((czm >> r) & 1u) << 31;
            sr[r] = f_u(u_f(sr[r]) ^ sgn);
            si[r] = f_u(u_f(si[r]) ^ sgn);
        }
    }

    // ---- expvals: Z wires 0..3 -> idx bits 11,10 (wv) and 9,8 (lane 5,4) ----
    float p = 0.f;
#pragma unroll
    for (int r = 0; r < AMPS; ++r) p = fmaf(sr[r], sr[r], fmaf(si[r], si[r], p));

    float v0 = ((wv   >> 1) & 1) ? -p : p;
    float v1 = ( wv         & 1) ? -p : p;
    float v2 = ((lane >> 5) & 1) ? -p : p;
    float v3 = ((lane >> 4) & 1) ? -p : p;
#pragma unroll
    for (int m = 1; m <= 32; m <<= 1) {
        v0 += __shfl_xor(v0, m);
        v1 += __shfl_xor(v1, m);
        v2 += __shfl_xor(v2, m);
        v3 += __shfl_xor(v3, m);
    }

    __syncthreads();   // LDS reuse for reduction
    if (lane == 0) xch[wv] = make_float4(v0, v1, v2, v3);
    __syncthreads();
    if (tid == 0) {
        float4 a0 = xch[0], a1 = xch[1], a2 = xch[2], a3 = xch[3];
        float4 o;
        o.x = (a0.x + a1.x + a2.x + a3.x) * oscale[0];
        o.y = (a0.y + a1.y + a2.y + a3.y) * oscale[1];
        o.z = (a0.z + a1.z + a2.z + a3.z) * oscale[2];
        o.w = (a0.w + a1.w + a2.w + a3.w) * oscale[3];
        *reinterpret_cast<float4*>(out + (size_t)b * 4) = o;
    }
}

extern "C" void kernel_launch(void* const* d_in, const int* in_sizes, int n_in,
                              void* d_out, int out_size, void* d_ws, size_t ws_size,
                              hipStream_t stream) {
    const float* x      = (const float*)d_in[0];
    const float* iscale = (const float*)d_in[1];
    const float* w      = (const float*)d_in[2];
    const float* oscale = (const float*)d_in[3];
    float* out          = (float*)d_out;

    const int batch = in_sizes[0] / (4 * NQ);
    qsim_kernel<<<batch, 256, 0, stream>>>(x, iscale, w, oscale, out, batch);
}

// Round 4
// 1115.369 us; speedup vs baseline: 1.0257x; 1.0257x over previous
//
#include <hip/hip_runtime.h>
#include <stdint.h>

#define NQ 12
#define NL 5
#define AMPS 16   // amplitudes per lane

// One 256-thread block (4 waves) per batch element. Amp index:
//   idx = (wv << 10) | (lane << 4) | r      (wv = wave 0..3, r = 0..15)
// Wire w <-> idx bit (11-w):
//   wires 0,1   -> wv bits 1,0   -> LDS exchange between wave pairs
//   wires 2..7  -> lane bits 5..0 -> cross-lane xor 32,16,8,4,2,1
//   wires 8..11 -> r bits 3..0   -> in-register pair butterfly
// amdgpu_waves_per_eu(4,4) pins the VGPR budget at 128: R3's (256,4) hint let
// the allocator shrink to 64 VGPRs targeting 8 waves/EU, spilling the state
// to scratch (1.15 GB HBM traffic/dispatch). State+temps need ~100 regs.

static __device__ __forceinline__ float f_u(unsigned u) { return __uint_as_float(u); }
static __device__ __forceinline__ unsigned u_f(float f) { return __float_as_uint(f); }

template <int CTRL>
static __device__ __forceinline__ float dpp_xor(float v) {
    int u = (int)__float_as_uint(v);
    return __uint_as_float((unsigned)__builtin_amdgcn_update_dpp(u, u, CTRL, 0xF, 0xF, false));
}
static __device__ __forceinline__ float swz_xor4(float v) {
    return f_u((unsigned)__builtin_amdgcn_ds_swizzle((int)u_f(v), 0x101F));
}

#define COEF(Q)                                                         \
    const float ar_ = f_u(__builtin_amdgcn_readlane(u_f(ar), (Q)));     \
    const float ai_ = f_u(__builtin_amdgcn_readlane(u_f(ai), (Q)));     \
    const float br_ = f_u(__builtin_amdgcn_readlane(u_f(br), (Q)));     \
    const float bi_ = f_u(__builtin_amdgcn_readlane(u_f(bi), (Q)));

// A/B form for wires where we fetch partner value o: out = A*s + B*o
#define AB_COEF(BIT)                                                    \
    const int   bit = (BIT);                                            \
    const float Ar = ar_;                                               \
    const float Ai = bit ? -ai_ : ai_;                                  \
    const float Br = bit ? -br_ : br_;                                  \
    const float Bi = bi_;

#define AB_GATE(OP)                                                     \
    _Pragma("unroll")                                                   \
    for (int r = 0; r < AMPS; ++r) {                                    \
        const float s_r = sr[r], s_i = si[r];                           \
        const float o_r = OP(s_r);                                      \
        const float o_i = OP(s_i);                                      \
        sr[r] = Ar * s_r - Ai * s_i + Br * o_r - Bi * o_i;              \
        si[r] = Ar * s_i + Ai * s_r + Br * o_i + Bi * o_r;              \
    }

// permlane-swap form: swap(v,v) -> {lo-half replicated, hi-half replicated};
// out = P*na + Q*nb, P/Q per-lane coefs (no per-amp select).
#define PQ_COEF(HB)                                                     \
    const int   hb = (HB);                                              \
    const float Pr = hb ? -br_ : ar_;                                   \
    const float Pi = hb ?  bi_ : ai_;                                   \
    const float Qr = hb ?  ar_ : br_;                                   \
    const float Qi = hb ? -ai_ : bi_;

#define PQ_GATE(SWAP)                                                   \
    _Pragma("unroll")                                                   \
    for (int r = 0; r < AMPS; ++r) {                                    \
        auto dr_ = SWAP(u_f(sr[r]), u_f(sr[r]), false, false);          \
        auto di_ = SWAP(u_f(si[r]), u_f(si[r]), false, false);          \
        const float nar = f_u(dr_[0]), nbr = f_u(dr_[1]);               \
        const float nai = f_u(di_[0]), nbi = f_u(di_[1]);               \
        sr[r] = Pr * nar - Pi * nai + Qr * nbr - Qi * nbi;              \
        si[r] = Pr * nai + Pi * nar + Qr * nbi + Qi * nbr;              \
    }

template <int ST>
static __device__ __forceinline__ void reg_gate(float (&sr)[AMPS], float (&si)[AMPS],
                                                float ar, float ai, float br, float bi) {
#pragma unroll
    for (int r0 = 0; r0 < AMPS; ++r0) {
        if (r0 & ST) continue;
        const int r1 = r0 | ST;
        const float s0r = sr[r0], s0i = si[r0];
        const float s1r = sr[r1], s1i = si[r1];
        sr[r0] =  ar * s0r - ai * s0i + br * s1r - bi * s1i;
        si[r0] =  ar * s0i + ai * s0r + br * s1i + bi * s1r;
        sr[r1] = -br * s0r - bi * s0i + ar * s1r + ai * s1i;
        si[r1] = -br * s0i + bi * s0r + ar * s1i - ai * s1r;
    }
}

__global__ __launch_bounds__(256)
__attribute__((amdgpu_waves_per_eu(4, 4)))
void qsim_kernel(
    const float* __restrict__ x,
    const float* __restrict__ iscale,
    const float* __restrict__ w,
    const float* __restrict__ oscale,
    float* __restrict__ out,
    int batch)
{
    const int tid  = threadIdx.x;
    const int lane = tid & 63;
    const int wv   = tid >> 6;
    const int b    = blockIdx.x;
    if (b >= batch) return;

    __shared__ float4 xch[8 * 256];   // [k:8][tid:256], 32 KB, conflict-free

    float sr[AMPS], si[AMPS];
#pragma unroll
    for (int r = 0; r < AMPS; ++r) { sr[r] = 0.f; si[r] = 0.f; }
    if (tid == 0) sr[0] = 1.f;

    // CZ-ring sign bits (16 per lane)
    unsigned czm = 0;
#pragma unroll
    for (int r = 0; r < AMPS; ++r) {
        unsigned idx  = ((unsigned)wv << 10) | ((unsigned)lane << 4) | (unsigned)r;
        unsigned adj  = (idx & (idx >> 1)) & 0x7FFu;
        unsigned wrap = (idx & (idx >> 11)) & 1u;
        czm |= (((unsigned)__popc(adj) + wrap) & 1u) << r;
    }

    const int ql = (lane < NQ) ? lane : 0;
    const float* xb = x + (size_t)b * (4 * NQ);

#pragma unroll 1
    for (int it = 0; it < NL * 3; ++it) {
        const int blk = it - 3 * (it / 3);

        // fused U = RZ*RY*RX for qubit ql (built by lanes 0..11)
        float f     = xb[NQ + blk * NQ + ql];
        float alpha = iscale[it * NQ + ql] * f;
        float beta  = w[it * 2 * NQ + ql];
        float gamma = w[it * 2 * NQ + NQ + ql];
        float sa, ca, sb, cb, sg, cg;
        sincosf(0.5f * alpha, &sa, &ca);
        sincosf(0.5f * beta,  &sb, &cb);
        sincosf(0.5f * gamma, &sg, &cg);
        float cbca = cb * ca, sbsa = sb * sa, sbca = sb * ca, cbsa = cb * sa;
        float ar =  cg * cbca + sg * sbsa;
        float ai =  cg * sbsa - sg * cbca;
        float br = -(cg * sbca + sg * cbsa);
        float bi =  sg * sbca - cg * cbsa;

        // ---- wave wires (qubits 0,1): LDS exchange ----
        {
            COEF(0); AB_COEF((wv >> 1) & 1);
            __syncthreads();   // prior LDS readers done
#pragma unroll
            for (int k = 0; k < 8; ++k)
                xch[(k << 8) + tid] = make_float4(sr[2*k], si[2*k], sr[2*k+1], si[2*k+1]);
            __syncthreads();
            const int ptid = tid ^ (2 << 6);
#pragma unroll
            for (int k = 0; k < 8; ++k) {
                float4 o = xch[(k << 8) + ptid];
                float s0r = sr[2*k], s0i = si[2*k];
                sr[2*k]   = Ar*s0r - Ai*s0i + Br*o.x - Bi*o.y;
                si[2*k]   = Ar*s0i + Ai*s0r + Br*o.y + Bi*o.x;
                float s1r = sr[2*k+1], s1i = si[2*k+1];
                sr[2*k+1] = Ar*s1r - Ai*s1i + Br*o.z - Bi*o.w;
                si[2*k+1] = Ar*s1i + Ai*s1r + Br*o.w + Bi*o.z;
            }
        }
        {
            COEF(1); AB_COEF(wv & 1);
            __syncthreads();
#pragma unroll
            for (int k = 0; k < 8; ++k)
                xch[(k << 8) + tid] = make_float4(sr[2*k], si[2*k], sr[2*k+1], si[2*k+1]);
            __syncthreads();
            const int ptid = tid ^ (1 << 6);
#pragma unroll
            for (int k = 0; k < 8; ++k) {
                float4 o = xch[(k << 8) + ptid];
                float s0r = sr[2*k], s0i = si[2*k];
                sr[2*k]   = Ar*s0r - Ai*s0i + Br*o.x - Bi*o.y;
                si[2*k]   = Ar*s0i + Ai*s0r + Br*o.y + Bi*o.x;
                float s1r = sr[2*k+1], s1i = si[2*k+1];
                sr[2*k+1] = Ar*s1r - Ai*s1i + Br*o.z - Bi*o.w;
                si[2*k+1] = Ar*s1i + Ai*s1r + Br*o.w + Bi*o.z;
            }
        }

        // ---- lane wires (qubits 2..7) ----
        { // qubit 2: xor32
            COEF(2);
#if __has_builtin(__builtin_amdgcn_permlane32_swap)
            PQ_COEF((lane >> 5) & 1);
            PQ_GATE(__builtin_amdgcn_permlane32_swap)
#else
            AB_COEF((lane >> 5) & 1);
#define X32(v) __shfl_xor((v), 32)
            AB_GATE(X32)
#undef X32
#endif
        }
        { // qubit 3: xor16
            COEF(3);
#if __has_builtin(__builtin_amdgcn_permlane16_swap)
            PQ_COEF((lane >> 4) & 1);
            PQ_GATE(__builtin_amdgcn_permlane16_swap)
#else
            AB_COEF((lane >> 4) & 1);
#define X16(v) __shfl_xor((v), 16)
            AB_GATE(X16)
#undef X16
#endif
        }
        { // qubit 4: xor8 -> DPP row_ror:8
            COEF(4); AB_COEF((lane >> 3) & 1);
            AB_GATE(dpp_xor<0x128>)
        }
        { // qubit 5: xor4 -> ds_swizzle
            COEF(5); AB_COEF((lane >> 2) & 1);
            AB_GATE(swz_xor4)
        }
        { // qubit 6: xor2 -> DPP quad_perm [2,3,0,1]
            COEF(6); AB_COEF((lane >> 1) & 1);
            AB_GATE(dpp_xor<0x4E>)
        }
        { // qubit 7: xor1 -> DPP quad_perm [1,0,3,2]
            COEF(7); AB_COEF(lane & 1);
            AB_GATE(dpp_xor<0xB1>)
        }

        // ---- register wires (qubits 8..11) ----
        { COEF(8);  reg_gate<8>(sr, si, ar_, ai_, br_, bi_); }
        { COEF(9);  reg_gate<4>(sr, si, ar_, ai_, br_, bi_); }
        { COEF(10); reg_gate<2>(sr, si, ar_, ai_, br_, bi_); }
        { COEF(11); reg_gate<1>(sr, si, ar_, ai_, br_, bi_); }

        // ---- CZ ring (diagonal +-1) ----
#pragma unroll
        for (int r = 0; r < AMPS; ++r) {
            const unsigned sgn = ((czm >> r) & 1u) << 31;
            sr[r] = f_u(u_f(sr[r]) ^ sgn);
            si[r] = f_u(u_f(si[r]) ^ sgn);
        }
    }

    // ---- expvals: Z wires 0..3 -> idx bits 11,10 (wv) and 9,8 (lane 5,4) ----
    float p = 0.f;
#pragma unroll
    for (int r = 0; r < AMPS; ++r) p = fmaf(sr[r], sr[r], fmaf(si[r], si[r], p));

    float v0 = ((wv   >> 1) & 1) ? -p : p;
    float v1 = ( wv         & 1) ? -p : p;
    float v2 = ((lane >> 5) & 1) ? -p : p;
    float v3 = ((lane >> 4) & 1) ? -p : p;
#pragma unroll
    for (int m = 1; m <= 32; m <<= 1) {
        v0 += __shfl_xor(v0, m);
        v1 += __shfl_xor(v1, m);
        v2 += __shfl_xor(v2, m);
        v3 += __shfl_xor(v3, m);
    }

    __syncthreads();   // LDS reuse for reduction
    if (lane == 0) xch[wv] = make_float4(v0, v1, v2, v3);
    __syncthreads();
    if (tid == 0) {
        float4 a0 = xch[0], a1 = xch[1], a2 = xch[2], a3 = xch[3];
        float4 o;
        o.x = (a0.x + a1.x + a2.x + a3.x) * oscale[0];
        o.y = (a0.y + a1.y + a2.y + a3.y) * oscale[1];
        o.z = (a0.z + a1.z + a2.z + a3.z) * oscale[2];
        o.w = (a0.w + a1.w + a2.w + a3.w) * oscale[3];
        *reinterpret_cast<float4*>(out + (size_t)b * 4) = o;
    }
}

extern "C" void kernel_launch(void* const* d_in, const int* in_sizes, int n_in,
                              void* d_out, int out_size, void* d_ws, size_t ws_size,
                              hipStream_t stream) {
    const float* x      = (const float*)d_in[0];
    const float* iscale = (const float*)d_in[1];
    const float* w      = (const float*)d_in[2];
    const float* oscale = (const float*)d_in[3];
    float* out          = (float*)d_out;

    const int batch = in_sizes[0] / (4 * NQ);
    qsim_kernel<<<batch, 256, 0, stream>>>(x, iscale, w, oscale, out, batch);
}

// Round 5
// 1091.984 us; speedup vs baseline: 1.0476x; 1.0214x over previous
//
#include <hip/hip_runtime.h>
#include <stdint.h>

#define NQ 12
#define NL 5
#define AMPS 16   // amplitudes per lane

// One 256-thread block (4 waves) per batch element. Amp index:
//   idx = (wv << 10) | (lane << 4) | r      (wv = wave 0..3, r = 0..15)
// Wire w <-> idx bit (11-w):
//   wires 0,1   -> wv bits 1,0   -> LDS exchange between wave pairs
//   wires 2..7  -> lane bits 5..0 -> cross-lane xor 32,16,8,4,2,1
//   wires 8..11 -> r bits 3..0   -> in-register pair butterfly
// NOTE: plain one-arg __launch_bounds__ ONLY. Both __launch_bounds__(256,4)
// and amdgpu_waves_per_eu(4,4) made the allocator target 8 waves/EU
// (VGPR_Count=64) and spill the state array (~650 MB scratch HBM traffic
// per dispatch, R3/R4). One-arg form gave a spill-free allocation in R2.

static __device__ __forceinline__ float f_u(unsigned u) { return __uint_as_float(u); }
static __device__ __forceinline__ unsigned u_f(float f) { return __float_as_uint(f); }

template <int CTRL>
static __device__ __forceinline__ float dpp_xor(float v) {
    int u = (int)__float_as_uint(v);
    return __uint_as_float((unsigned)__builtin_amdgcn_update_dpp(u, u, CTRL, 0xF, 0xF, false));
}
static __device__ __forceinline__ float swz_xor4(float v) {
    return f_u((unsigned)__builtin_amdgcn_ds_swizzle((int)u_f(v), 0x101F));
}

#define COEF(Q)                                                         \
    const float ar_ = f_u(__builtin_amdgcn_readlane(u_f(ar), (Q)));     \
    const float ai_ = f_u(__builtin_amdgcn_readlane(u_f(ai), (Q)));     \
    const float br_ = f_u(__builtin_amdgcn_readlane(u_f(br), (Q)));     \
    const float bi_ = f_u(__builtin_amdgcn_readlane(u_f(bi), (Q)));

// A/B form for wires where we fetch partner value o: out = A*s + B*o
#define AB_COEF(BIT)                                                    \
    const int   bit = (BIT);                                            \
    const float Ar = ar_;                                               \
    const float Ai = bit ? -ai_ : ai_;                                  \
    const float Br = bit ? -br_ : br_;                                  \
    const float Bi = bi_;

#define AB_GATE(OP)                                                     \
    _Pragma("unroll")                                                   \
    for (int r = 0; r < AMPS; ++r) {                                    \
        const float s_r = sr[r], s_i = si[r];                           \
        const float o_r = OP(s_r);                                      \
        const float o_i = OP(s_i);                                      \
        sr[r] = Ar * s_r - Ai * s_i + Br * o_r - Bi * o_i;              \
        si[r] = Ar * s_i + Ai * s_r + Br * o_i + Bi * o_r;              \
    }

// permlane-swap form: swap(v,v) -> {lo-half replicated, hi-half replicated};
// out = P*na + Q*nb, P/Q per-lane coefs (no per-amp select).
#define PQ_COEF(HB)                                                     \
    const int   hb = (HB);                                              \
    const float Pr = hb ? -br_ : ar_;                                   \
    const float Pi = hb ?  bi_ : ai_;                                   \
    const float Qr = hb ?  ar_ : br_;                                   \
    const float Qi = hb ? -ai_ : bi_;

#define PQ_GATE(SWAP)                                                   \
    _Pragma("unroll")                                                   \
    for (int r = 0; r < AMPS; ++r) {                                    \
        auto dr_ = SWAP(u_f(sr[r]), u_f(sr[r]), false, false);          \
        auto di_ = SWAP(u_f(si[r]), u_f(si[r]), false, false);          \
        const float nar = f_u(dr_[0]), nbr = f_u(dr_[1]);               \
        const float nai = f_u(di_[0]), nbi = f_u(di_[1]);               \
        sr[r] = Pr * nar - Pi * nai + Qr * nbr - Qi * nbi;              \
        si[r] = Pr * nai + Pi * nar + Qr * nbi + Qi * nbr;              \
    }

template <int ST>
static __device__ __forceinline__ void reg_gate(float (&sr)[AMPS], float (&si)[AMPS],
                                                float ar, float ai, float br, float bi) {
#pragma unroll
    for (int r0 = 0; r0 < AMPS; ++r0) {
        if (r0 & ST) continue;
        const int r1 = r0 | ST;
        const float s0r = sr[r0], s0i = si[r0];
        const float s1r = sr[r1], s1i = si[r1];
        sr[r0] =  ar * s0r - ai * s0i + br * s1r - bi * s1i;
        si[r0] =  ar * s0i + ai * s0r + br * s1i + bi * s1r;
        sr[r1] = -br * s0r - bi * s0i + ar * s1r + ai * s1i;
        si[r1] = -br * s0i + bi * s0r + ar * s1i - ai * s1r;
    }
}

__global__ __launch_bounds__(256)
void qsim_kernel(
    const float* __restrict__ x,
    const float* __restrict__ iscale,
    const float* __restrict__ w,
    const float* __restrict__ oscale,
    float* __restrict__ out,
    int batch)
{
    const int tid  = threadIdx.x;
    const int lane = tid & 63;
    const int wv   = tid >> 6;
    const int b    = blockIdx.x;
    if (b >= batch) return;

    __shared__ float4 xch[8 * 256];   // [k:8][tid:256], 32 KB, conflict-free

    float sr[AMPS], si[AMPS];
#pragma unroll
    for (int r = 0; r < AMPS; ++r) { sr[r] = 0.f; si[r] = 0.f; }
    if (tid == 0) sr[0] = 1.f;

    // CZ-ring sign bits (16 per lane)
    unsigned czm = 0;
#pragma unroll
    for (int r = 0; r < AMPS; ++r) {
        unsigned idx  = ((unsigned)wv << 10) | ((unsigned)lane << 4) | (unsigned)r;
        unsigned adj  = (idx & (idx >> 1)) & 0x7FFu;
        unsigned wrap = (idx & (idx >> 11)) & 1u;
        czm |= (((unsigned)__popc(adj) + wrap) & 1u) << r;
    }

    const int ql = (lane < NQ) ? lane : 0;
    const float* xb = x + (size_t)b * (4 * NQ);

#pragma unroll 1
    for (int it = 0; it < NL * 3; ++it) {
        const int blk = it - 3 * (it / 3);

        // fused U = RZ*RY*RX for qubit ql (built by lanes 0..11)
        float f     = xb[NQ + blk * NQ + ql];
        float alpha = iscale[it * NQ + ql] * f;
        float beta  = w[it * 2 * NQ + ql];
        float gamma = w[it * 2 * NQ + NQ + ql];
        float sa, ca, sb, cb, sg, cg;
        sincosf(0.5f * alpha, &sa, &ca);
        sincosf(0.5f * beta,  &sb, &cb);
        sincosf(0.5f * gamma, &sg, &cg);
        float cbca = cb * ca, sbsa = sb * sa, sbca = sb * ca, cbsa = cb * sa;
        float ar =  cg * cbca + sg * sbsa;
        float ai =  cg * sbsa - sg * cbca;
        float br = -(cg * sbca + sg * cbsa);
        float bi =  sg * sbca - cg * cbsa;

        // ---- wave wires (qubits 0,1): LDS exchange ----
        {
            COEF(0); AB_COEF((wv >> 1) & 1);
            __syncthreads();   // prior LDS readers done
#pragma unroll
            for (int k = 0; k < 8; ++k)
                xch[(k << 8) + tid] = make_float4(sr[2*k], si[2*k], sr[2*k+1], si[2*k+1]);
            __syncthreads();
            const int ptid = tid ^ (2 << 6);
#pragma unroll
            for (int k = 0; k < 8; ++k) {
                float4 o = xch[(k << 8) + ptid];
                float s0r = sr[2*k], s0i = si[2*k];
                sr[2*k]   = Ar*s0r - Ai*s0i + Br*o.x - Bi*o.y;
                si[2*k]   = Ar*s0i + Ai*s0r + Br*o.y + Bi*o.x;
                float s1r = sr[2*k+1], s1i = si[2*k+1];
                sr[2*k+1] = Ar*s1r - Ai*s1i + Br*o.z - Bi*o.w;
                si[2*k+1] = Ar*s1i + Ai*s1r + Br*o.w + Bi*o.z;
            }
        }
        {
            COEF(1); AB_COEF(wv & 1);
            __syncthreads();
#pragma unroll
            for (int k = 0; k < 8; ++k)
                xch[(k << 8) + tid] = make_float4(sr[2*k], si[2*k], sr[2*k+1], si[2*k+1]);
            __syncthreads();
            const int ptid = tid ^ (1 << 6);
#pragma unroll
            for (int k = 0; k < 8; ++k) {
                float4 o = xch[(k << 8) + ptid];
                float s0r = sr[2*k], s0i = si[2*k];
                sr[2*k]   = Ar*s0r - Ai*s0i + Br*o.x - Bi*o.y;
                si[2*k]   = Ar*s0i + Ai*s0r + Br*o.y + Bi*o.x;
                float s1r = sr[2*k+1], s1i = si[2*k+1];
                sr[2*k+1] = Ar*s1r - Ai*s1i + Br*o.z - Bi*o.w;
                si[2*k+1] = Ar*s1i + Ai*s1r + Br*o.w + Bi*o.z;
            }
        }

        // ---- lane wires (qubits 2..7) ----
        { // qubit 2: xor32
            COEF(2);
#if __has_builtin(__builtin_amdgcn_permlane32_swap)
            PQ_COEF((lane >> 5) & 1);
            PQ_GATE(__builtin_amdgcn_permlane32_swap)
#else
            AB_COEF((lane >> 5) & 1);
#define X32(v) __shfl_xor((v), 32)
            AB_GATE(X32)
#undef X32
#endif
        }
        { // qubit 3: xor16
            COEF(3);
#if __has_builtin(__builtin_amdgcn_permlane16_swap)
            PQ_COEF((lane >> 4) & 1);
            PQ_GATE(__builtin_amdgcn_permlane16_swap)
#else
            AB_COEF((lane >> 4) & 1);
#define X16(v) __shfl_xor((v), 16)
            AB_GATE(X16)
#undef X16
#endif
        }
        { // qubit 4: xor8 -> DPP row_ror:8
            COEF(4); AB_COEF((lane >> 3) & 1);
            AB_GATE(dpp_xor<0x128>)
        }
        { // qubit 5: xor4 -> ds_swizzle
            COEF(5); AB_COEF((lane >> 2) & 1);
            AB_GATE(swz_xor4)
        }
        { // qubit 6: xor2 -> DPP quad_perm [2,3,0,1]
            COEF(6); AB_COEF((lane >> 1) & 1);
            AB_GATE(dpp_xor<0x4E>)
        }
        { // qubit 7: xor1 -> DPP quad_perm [1,0,3,2]
            COEF(7); AB_COEF(lane & 1);
            AB_GATE(dpp_xor<0xB1>)
        }

        // ---- register wires (qubits 8..11) ----
        { COEF(8);  reg_gate<8>(sr, si, ar_, ai_, br_, bi_); }
        { COEF(9);  reg_gate<4>(sr, si, ar_, ai_, br_, bi_); }
        { COEF(10); reg_gate<2>(sr, si, ar_, ai_, br_, bi_); }
        { COEF(11); reg_gate<1>(sr, si, ar_, ai_, br_, bi_); }

        // ---- CZ ring (diagonal +-1) ----
#pragma unroll
        for (int r = 0; r < AMPS; ++r) {
            const unsigned sgn = ((czm >> r) & 1u) << 31;
            sr[r] = f_u(u_f(sr[r]) ^ sgn);
            si[r] = f_u(u_f(si[r]) ^ sgn);
        }
    }

    // ---- expvals: Z wires 0..3 -> idx bits 11,10 (wv) and 9,8 (lane 5,4) ----
    float p = 0.f;
#pragma unroll
    for (int r = 0; r < AMPS; ++r) p = fmaf(sr[r], sr[r], fmaf(si[r], si[r], p));

    float v0 = ((wv   >> 1) & 1) ? -p : p;
    float v1 = ( wv         & 1) ? -p : p;
    float v2 = ((lane >> 5) & 1) ? -p : p;
    float v3 = ((lane >> 4) & 1) ? -p : p;
#pragma unroll
    for (int m = 1; m <= 32; m <<= 1) {
        v0 += __shfl_xor(v0, m);
        v1 += __shfl_xor(v1, m);
        v2 += __shfl_xor(v2, m);
        v3 += __shfl_xor(v3, m);
    }

    __syncthreads();   // LDS reuse for reduction
    if (lane == 0) xch[wv] = make_float4(v0, v1, v2, v3);
    __syncthreads();
    if (tid == 0) {
        float4 a0 = xch[0], a1 = xch[1], a2 = xch[2], a3 = xch[3];
        float4 o;
        o.x = (a0.x + a1.x + a2.x + a3.x) * oscale[0];
        o.y = (a0.y + a1.y + a2.y + a3.y) * oscale[1];
        o.z = (a0.z + a1.z + a2.z + a3.z) * oscale[2];
        o.w = (a0.w + a1.w + a2.w + a3.w) * oscale[3];
        *reinterpret_cast<float4*>(out + (size_t)b * 4) = o;
    }
}

extern "C" void kernel_launch(void* const* d_in, const int* in_sizes, int n_in,
                              void* d_out, int out_size, void* d_ws, size_t ws_size,
                              hipStream_t stream) {
    const float* x      = (const float*)d_in[0];
    const float* iscale = (const float*)d_in[1];
    const float* w      = (const float*)d_in[2];
    const float* oscale = (const float*)d_in[3];
    float* out          = (float*)d_out;

    const int batch = in_sizes[0] / (4 * NQ);
    qsim_kernel<<<batch, 256, 0, stream>>>(x, iscale, w, oscale, out, batch);
}

// Round 6
// 610.444 us; speedup vs baseline: 1.8741x; 1.7888x over previous
//
#include <hip/hip_runtime.h>
#include <stdint.h>

#define NQ 12
#define NL 5
#define AMPS 16   // amplitudes per lane

// One 256-thread block (4 waves) per batch element. Amp index:
//   idx = (wv << 10) | (lane << 4) | r      (wv = wave 0..3, r = 0..15)
// Wire w <-> idx bit (11-w):
//   wires 0,1   -> wv bits 1,0   -> LDS exchange between wave pairs
//   wires 2..7  -> lane bits 5..0 -> cross-lane xor 32,16,8,4,2,1
//   wires 8..11 -> r bits 3..0   -> in-register pair butterfly
// State is float2-interleaved (re,im) per amp; all complex updates use
// packed fp32 VOP3P (v_pk_mul_f32 / v_pk_fma_f32) with op_sel half-swaps
// and neg_lo/neg_hi sign masks: 4 instrs per amp per gate (was 8 scalar).
// NOTE: plain one-arg __launch_bounds__ ONLY (R3/R4: min-waves hints made
// the allocator target 8 waves/EU -> VGPR 64 -> state spilled to scratch).

typedef float f2 __attribute__((ext_vector_type(2)));

static __device__ __forceinline__ float f_u(unsigned u) { return __uint_as_float(u); }
static __device__ __forceinline__ unsigned u_f(float f) { return __float_as_uint(f); }

// ---- packed complex primitives ----
// acc = (Cr*Sr, Cr*Si)
#define PK_MUL_RR(acc, C, S) \
    asm("v_pk_mul_f32 %0, %1, %2 op_sel_hi:[0,1]" : "=v"(acc) : "v"(C), "v"(S))
// acc += (-Ci*Si, +Ci*Sr)   [C-imag cross term]
#define PK_FMA_I(acc, C, S) \
    asm("v_pk_fma_f32 %0, %1, %2, %0 op_sel:[1,1,0] op_sel_hi:[1,0,1] neg_lo:[1,0,0]" \
        : "+v"(acc) : "v"(C), "v"(S))
// acc += (Cr*Sr, Cr*Si)
#define PK_FMA_R(acc, C, S) \
    asm("v_pk_fma_f32 %0, %1, %2, %0 op_sel_hi:[0,1,1]" : "+v"(acc) : "v"(C), "v"(S))
// acc += (+Ci*Si, -Ci*Sr)   [conj(C) cross term]
#define PK_FMA_IC(acc, C, S) \
    asm("v_pk_fma_f32 %0, %1, %2, %0 op_sel:[1,1,0] op_sel_hi:[1,0,1] neg_hi:[1,0,0]" \
        : "+v"(acc) : "v"(C), "v"(S))
// acc += (-Cr*Sr, -Cr*Si)
#define PK_FMA_RN(acc, C, S) \
    asm("v_pk_fma_f32 %0, %1, %2, %0 op_sel_hi:[0,1,1] neg_lo:[1,0,0] neg_hi:[1,0,0]" \
        : "+v"(acc) : "v"(C), "v"(S))

// t = CA (.) s + CB (.) o   (complex mul-add, 4 pk instrs + copy)
#define CPLX_AB(DST, CA, S, CB, O)                                    \
    { f2 t_;                                                          \
      PK_MUL_RR(t_, CA, S); PK_FMA_I(t_, CA, S);                      \
      PK_FMA_R (t_, CB, O); PK_FMA_I(t_, CB, O);                      \
      DST = t_; }

template <int CTRL>
static __device__ __forceinline__ float dpp_xor(float v) {
    int u = (int)__float_as_uint(v);
    return __uint_as_float((unsigned)__builtin_amdgcn_update_dpp(u, u, CTRL, 0xF, 0xF, false));
}
static __device__ __forceinline__ float swz_xor4(float v) {
    return f_u((unsigned)__builtin_amdgcn_ds_swizzle((int)u_f(v), 0x101F));
}

#define COEF(Q)                                                         \
    const float ar_ = f_u(__builtin_amdgcn_readlane(u_f(ar), (Q)));     \
    const float ai_ = f_u(__builtin_amdgcn_readlane(u_f(ai), (Q)));     \
    const float br_ = f_u(__builtin_amdgcn_readlane(u_f(br), (Q)));     \
    const float bi_ = f_u(__builtin_amdgcn_readlane(u_f(bi), (Q)));

// AB gate over all amps: o = OPX(s) elementwise (cross-lane xor)
#define AB_GATE_PK(OPX)                                                 \
    _Pragma("unroll")                                                   \
    for (int r = 0; r < AMPS; ++r) {                                    \
        f2 o; o.x = OPX(s[r].x); o.y = OPX(s[r].y);                     \
        CPLX_AB(s[r], CA, s[r], CB, o)                                  \
    }

// Register-bit wire: out0 = a(.)s0 + b(.)s1 ; out1 = -conj(b)(.)s0 + conj(a)(.)s1
template <int ST>
static __device__ __forceinline__ void reg_gate_pk(f2 (&s)[AMPS], f2 CAg, f2 CBg) {
#pragma unroll
    for (int r0 = 0; r0 < AMPS; ++r0) {
        if (r0 & ST) continue;
        const int r1 = r0 | ST;
        const f2 s0 = s[r0], s1 = s[r1];
        f2 t0, t1;
        PK_MUL_RR(t0, CAg, s0); PK_FMA_I (t0, CAg, s0);
        PK_FMA_R (t0, CBg, s1); PK_FMA_I (t0, CBg, s1);
        PK_MUL_RR(t1, CAg, s1); PK_FMA_IC(t1, CAg, s1);
        PK_FMA_RN(t1, CBg, s0); PK_FMA_I (t1, CBg, s0);
        s[r0] = t0; s[r1] = t1;
    }
}

__global__ __launch_bounds__(256)
void qsim_kernel(
    const float* __restrict__ x,
    const float* __restrict__ iscale,
    const float* __restrict__ w,
    const float* __restrict__ oscale,
    float* __restrict__ out,
    int batch)
{
    const int tid  = threadIdx.x;
    const int lane = tid & 63;
    const int wv   = tid >> 6;
    const int b    = blockIdx.x;
    if (b >= batch) return;

    __shared__ float4 xch[8 * 256];   // [k:8][tid:256], 32 KB, conflict-free

    f2 s[AMPS];
#pragma unroll
    for (int r = 0; r < AMPS; ++r) { s[r].x = 0.f; s[r].y = 0.f; }
    if (tid == 0) s[0].x = 1.f;

    // CZ-ring sign bits (16 per lane)
    unsigned czm = 0;
#pragma unroll
    for (int r = 0; r < AMPS; ++r) {
        unsigned idx  = ((unsigned)wv << 10) | ((unsigned)lane << 4) | (unsigned)r;
        unsigned adj  = (idx & (idx >> 1)) & 0x7FFu;
        unsigned wrap = (idx & (idx >> 11)) & 1u;
        czm |= (((unsigned)__popc(adj) + wrap) & 1u) << r;
    }

    const int ql = (lane < NQ) ? lane : 0;
    const float* xb = x + (size_t)b * (4 * NQ);

#pragma unroll 1
    for (int it = 0; it < NL * 3; ++it) {
        const int blk = it - 3 * (it / 3);

        // fused U = RZ*RY*RX for qubit ql (built by lanes 0..11)
        float f     = xb[NQ + blk * NQ + ql];
        float alpha = iscale[it * NQ + ql] * f;
        float beta  = w[it * 2 * NQ + ql];
        float gamma = w[it * 2 * NQ + NQ + ql];
        float sa, ca, sb, cb, sg, cg;
        sincosf(0.5f * alpha, &sa, &ca);
        sincosf(0.5f * beta,  &sb, &cb);
        sincosf(0.5f * gamma, &sg, &cg);
        float cbca = cb * ca, sbsa = sb * sa, sbca = sb * ca, cbsa = cb * sa;
        float ar =  cg * cbca + sg * sbsa;
        float ai =  cg * sbsa - sg * cbca;
        float br = -(cg * sbca + sg * cbsa);
        float bi =  sg * sbca - cg * cbsa;

        // ---- wave wires (qubits 0,1): LDS exchange ----
        {
            COEF(0);
            const int bit = (wv >> 1) & 1;
            const f2 CA = { ar_, bit ? -ai_ : ai_ };
            const f2 CB = { bit ? -br_ : br_, bi_ };
            __syncthreads();   // prior LDS readers done
#pragma unroll
            for (int k = 0; k < 8; ++k)
                xch[(k << 8) + tid] = make_float4(s[2*k].x, s[2*k].y, s[2*k+1].x, s[2*k+1].y);
            __syncthreads();
            const int ptid = tid ^ (2 << 6);
#pragma unroll
            for (int k = 0; k < 8; ++k) {
                float4 o4 = xch[(k << 8) + ptid];
                f2 oA = { o4.x, o4.y }, oB = { o4.z, o4.w };
                CPLX_AB(s[2*k],   CA, s[2*k],   CB, oA)
                CPLX_AB(s[2*k+1], CA, s[2*k+1], CB, oB)
            }
        }
        {
            COEF(1);
            const int bit = wv & 1;
            const f2 CA = { ar_, bit ? -ai_ : ai_ };
            const f2 CB = { bit ? -br_ : br_, bi_ };
            __syncthreads();
#pragma unroll
            for (int k = 0; k < 8; ++k)
                xch[(k << 8) + tid] = make_float4(s[2*k].x, s[2*k].y, s[2*k+1].x, s[2*k+1].y);
            __syncthreads();
            const int ptid = tid ^ (1 << 6);
#pragma unroll
            for (int k = 0; k < 8; ++k) {
                float4 o4 = xch[(k << 8) + ptid];
                f2 oA = { o4.x, o4.y }, oB = { o4.z, o4.w };
                CPLX_AB(s[2*k],   CA, s[2*k],   CB, oA)
                CPLX_AB(s[2*k+1], CA, s[2*k+1], CB, oB)
            }
        }

        // ---- lane wires (qubits 2..7) ----
        { // qubit 2: xor32 -> permlane32_swap; out = P(.)na + Q(.)nb
            COEF(2);
            const int hb = (lane >> 5) & 1;
            const f2 CP = { hb ? -br_ : ar_, hb ?  bi_ : ai_ };
            const f2 CQ = { hb ?  ar_ : br_, hb ? -ai_ : bi_ };
#pragma unroll
            for (int r = 0; r < AMPS; ++r) {
                auto dx = __builtin_amdgcn_permlane32_swap(u_f(s[r].x), u_f(s[r].x), false, false);
                auto dy = __builtin_amdgcn_permlane32_swap(u_f(s[r].y), u_f(s[r].y), false, false);
                f2 na = { f_u(dx[0]), f_u(dy[0]) };
                f2 nb = { f_u(dx[1]), f_u(dy[1]) };
                CPLX_AB(s[r], CP, na, CQ, nb)
            }
        }
        { // qubit 3: xor16 -> permlane16_swap
            COEF(3);
            const int hb = (lane >> 4) & 1;
            const f2 CP = { hb ? -br_ : ar_, hb ?  bi_ : ai_ };
            const f2 CQ = { hb ?  ar_ : br_, hb ? -ai_ : bi_ };
#pragma unroll
            for (int r = 0; r < AMPS; ++r) {
                auto dx = __builtin_amdgcn_permlane16_swap(u_f(s[r].x), u_f(s[r].x), false, false);
                auto dy = __builtin_amdgcn_permlane16_swap(u_f(s[r].y), u_f(s[r].y), false, false);
                f2 na = { f_u(dx[0]), f_u(dy[0]) };
                f2 nb = { f_u(dx[1]), f_u(dy[1]) };
                CPLX_AB(s[r], CP, na, CQ, nb)
            }
        }
        { // qubit 4: xor8 -> DPP row_ror:8
            COEF(4);
            const int bit = (lane >> 3) & 1;
            const f2 CA = { ar_, bit ? -ai_ : ai_ };
            const f2 CB = { bit ? -br_ : br_, bi_ };
            AB_GATE_PK(dpp_xor<0x128>)
        }
        { // qubit 5: xor4 -> ds_swizzle
            COEF(5);
            const int bit = (lane >> 2) & 1;
            const f2 CA = { ar_, bit ? -ai_ : ai_ };
            const f2 CB = { bit ? -br_ : br_, bi_ };
            AB_GATE_PK(swz_xor4)
        }
        { // qubit 6: xor2 -> DPP quad_perm [2,3,0,1]
            COEF(6);
            const int bit = (lane >> 1) & 1;
            const f2 CA = { ar_, bit ? -ai_ : ai_ };
            const f2 CB = { bit ? -br_ : br_, bi_ };
            AB_GATE_PK(dpp_xor<0x4E>)
        }
        { // qubit 7: xor1 -> DPP quad_perm [1,0,3,2]
            COEF(7);
            const int bit = lane & 1;
            const f2 CA = { ar_, bit ? -ai_ : ai_ };
            const f2 CB = { bit ? -br_ : br_, bi_ };
            AB_GATE_PK(dpp_xor<0xB1>)
        }

        // ---- register wires (qubits 8..11) ----
        { COEF(8);  const f2 CAg = { ar_, ai_ }, CBg = { br_, bi_ }; reg_gate_pk<8>(s, CAg, CBg); }
        { COEF(9);  const f2 CAg = { ar_, ai_ }, CBg = { br_, bi_ }; reg_gate_pk<4>(s, CAg, CBg); }
        { COEF(10); const f2 CAg = { ar_, ai_ }, CBg = { br_, bi_ }; reg_gate_pk<2>(s, CAg, CBg); }
        { COEF(11); const f2 CAg = { ar_, ai_ }, CBg = { br_, bi_ }; reg_gate_pk<1>(s, CAg, CBg); }

        // ---- CZ ring (diagonal +-1) ----
#pragma unroll
        for (int r = 0; r < AMPS; ++r) {
            const unsigned sgn = ((czm >> r) & 1u) << 31;
            s[r].x = f_u(u_f(s[r].x) ^ sgn);
            s[r].y = f_u(u_f(s[r].y) ^ sgn);
        }
    }

    // ---- expvals: Z wires 0..3 -> idx bits 11,10 (wv) and 9,8 (lane 5,4) ----
    float p = 0.f;
#pragma unroll
    for (int r = 0; r < AMPS; ++r) p = fmaf(s[r].x, s[r].x, fmaf(s[r].y, s[r].y, p));

    float v0 = ((wv   >> 1) & 1) ? -p : p;
    float v1 = ( wv         & 1) ? -p : p;
    float v2 = ((lane >> 5) & 1) ? -p : p;
    float v3 = ((lane >> 4) & 1) ? -p : p;
#pragma unroll
    for (int m = 1; m <= 32; m <<= 1) {
        v0 += __shfl_xor(v0, m);
        v1 += __shfl_xor(v1, m);
        v2 += __shfl_xor(v2, m);
        v3 += __shfl_xor(v3, m);
    }

    __syncthreads();   // LDS reuse for reduction
    if (lane == 0) xch[wv] = make_float4(v0, v1, v2, v3);
    __syncthreads();
    if (tid == 0) {
        float4 a0 = xch[0], a1 = xch[1], a2 = xch[2], a3 = xch[3];
        float4 o;
        o.x = (a0.x + a1.x + a2.x + a3.x) * oscale[0];
        o.y = (a0.y + a1.y + a2.y + a3.y) * oscale[1];
        o.z = (a0.z + a1.z + a2.z + a3.z) * oscale[2];
        o.w = (a0.w + a1.w + a2.w + a3.w) * oscale[3];
        *reinterpret_cast<float4*>(out + (size_t)b * 4) = o;
    }
}

extern "C" void kernel_launch(void* const* d_in, const int* in_sizes, int n_in,
                              void* d_out, int out_size, void* d_ws, size_t ws_size,
                              hipStream_t stream) {
    const float* x      = (const float*)d_in[0];
    const float* iscale = (const float*)d_in[1];
    const float* w      = (const float*)d_in[2];
    const float* oscale = (const float*)d_in[3];
    float* out          = (float*)d_out;

    const int batch = in_sizes[0] / (4 * NQ);
    qsim_kernel<<<batch, 256, 0, stream>>>(x, iscale, w, oscale, out, batch);
}

// Round 7
// 537.450 us; speedup vs baseline: 2.1286x; 1.1358x over previous
//
#include <hip/hip_runtime.h>
#include <stdint.h>

#define NQ 12
#define NL 5
#define NIT 15
#define AMPS 16   // amplitudes per lane

// One 256-thread block (4 waves) per batch element. Amp index:
//   idx = (wv << 10) | (lane << 4) | r      (wv = wave 0..3, r = 0..15)
// Wire w <-> idx bit (11-w):
//   wires 0,1   -> wv bits 1,0  -> ONE fused 4-way LDS exchange (2-qubit gate)
//   wires 2..7  -> lane bits    -> permlane32/16_swap, DPP, ds_swizzle
//   wires 8..11 -> r bits 3..0  -> in-register pair butterfly
// All gate matrices precomputed ONCE into LDS (prologue, precise sincosf);
// per-iter coefs are 12 broadcast ds_read_b128 + sign flips.
// Packed fp32 VOP3P (v_pk_mul/fma_f32 + op_sel/neg masks): 4 instr/amp/gate.
// NOTE: plain one-arg __launch_bounds__ ONLY (min-waves hints -> VGPR 64 ->
// state spills, R3/R4).

typedef float f2 __attribute__((ext_vector_type(2)));

static __device__ __forceinline__ float f_u(unsigned u) { return __uint_as_float(u); }
static __device__ __forceinline__ unsigned u_f(float f) { return __float_as_uint(f); }

// ---- packed complex primitives ----
// acc = (Cr*Sr, Cr*Si)
#define PK_MUL_RR(acc, C, S) \
    asm("v_pk_mul_f32 %0, %1, %2 op_sel_hi:[0,1]" : "=v"(acc) : "v"(C), "v"(S))
// acc += (-Ci*Si, +Ci*Sr)
#define PK_FMA_I(acc, C, S) \
    asm("v_pk_fma_f32 %0, %1, %2, %0 op_sel:[1,1,0] op_sel_hi:[1,0,1] neg_lo:[1,0,0]" \
        : "+v"(acc) : "v"(C), "v"(S))
// acc += (Cr*Sr, Cr*Si)
#define PK_FMA_R(acc, C, S) \
    asm("v_pk_fma_f32 %0, %1, %2, %0 op_sel_hi:[0,1,1]" : "+v"(acc) : "v"(C), "v"(S))
// acc += (+Ci*Si, -Ci*Sr)   [conj cross term]
#define PK_FMA_IC(acc, C, S) \
    asm("v_pk_fma_f32 %0, %1, %2, %0 op_sel:[1,1,0] op_sel_hi:[1,0,1] neg_hi:[1,0,0]" \
        : "+v"(acc) : "v"(C), "v"(S))
// acc += (-Cr*Sr, -Cr*Si)
#define PK_FMA_RN(acc, C, S) \
    asm("v_pk_fma_f32 %0, %1, %2, %0 op_sel_hi:[0,1,1] neg_lo:[1,0,0] neg_hi:[1,0,0]" \
        : "+v"(acc) : "v"(C), "v"(S))

// complex product: DST = CA (x) CB
#define CMUL(DST, CA, CB) \
    { PK_MUL_RR(DST, CA, CB); PK_FMA_I(DST, CA, CB); }

// DST = CA (.) S + CB (.) O
#define CPLX_AB(DST, CA, S, CB, O)                                    \
    { f2 t_;                                                          \
      PK_MUL_RR(t_, CA, S); PK_FMA_I(t_, CA, S);                      \
      PK_FMA_R (t_, CB, O); PK_FMA_I(t_, CB, O);                      \
      DST = t_; }

template <int CTRL>
static __device__ __forceinline__ float dpp_xor(float v) {
    int u = (int)__float_as_uint(v);
    return __uint_as_float((unsigned)__builtin_amdgcn_update_dpp(u, u, CTRL, 0xF, 0xF, false));
}
static __device__ __forceinline__ float swz_xor4(float v) {
    return f_u((unsigned)__builtin_amdgcn_ds_swizzle((int)u_f(v), 0x101F));
}

// AB gate over all amps: o = OPX(s) elementwise (cross-lane xor)
#define AB_GATE_PK(OPX)                                                 \
    _Pragma("unroll")                                                   \
    for (int r = 0; r < AMPS; ++r) {                                    \
        f2 o; o.x = OPX(s[r].x); o.y = OPX(s[r].y);                     \
        CPLX_AB(s[r], CA, s[r], CB, o)                                  \
    }

// Register-bit wire
template <int ST>
static __device__ __forceinline__ void reg_gate_pk(f2 (&s)[AMPS], f2 CAg, f2 CBg) {
#pragma unroll
    for (int r0 = 0; r0 < AMPS; ++r0) {
        if (r0 & ST) continue;
        const int r1 = r0 | ST;
        const f2 s0 = s[r0], s1 = s[r1];
        f2 t0, t1;
        PK_MUL_RR(t0, CAg, s0); PK_FMA_I (t0, CAg, s0);
        PK_FMA_R (t0, CBg, s1); PK_FMA_I (t0, CBg, s1);
        PK_MUL_RR(t1, CAg, s1); PK_FMA_IC(t1, CAg, s1);
        PK_FMA_RN(t1, CBg, s0); PK_FMA_I (t1, CBg, s0);
        s[r0] = t0; s[r1] = t1;
    }
}

__global__ __launch_bounds__(256)
void qsim_kernel(
    const float* __restrict__ x,
    const float* __restrict__ iscale,
    const float* __restrict__ w,
    const float* __restrict__ oscale,
    float* __restrict__ out,
    int batch)
{
    const int tid  = threadIdx.x;
    const int lane = tid & 63;
    const int wv   = tid >> 6;
    const int b    = blockIdx.x;

    __shared__ float4 xch[8 * 256];     // 32 KB exchange buffer
    __shared__ float4 coef[NIT * NQ];   // 2.88 KB gate-matrix table

    // ---- prologue: build all 180 fused gate matrices (precise sincosf) ----
    if (tid < NIT * NQ) {
        const int it  = tid / NQ;
        const int q   = tid - it * NQ;
        const int blk = it - 3 * (it / 3);
        const float* xb = x + (size_t)b * (4 * NQ);
        float f     = xb[NQ + blk * NQ + q];
        float alpha = iscale[it * NQ + q] * f;
        float beta  = w[it * 2 * NQ + q];
        float gamma = w[it * 2 * NQ + NQ + q];
        float sa, ca, sb, cb, sg, cg;
        sincosf(0.5f * alpha, &sa, &ca);
        sincosf(0.5f * beta,  &sb, &cb);
        sincosf(0.5f * gamma, &sg, &cg);
        float cbca = cb * ca, sbsa = sb * sa, sbca = sb * ca, cbsa = cb * sa;
        float ar =  cg * cbca + sg * sbsa;
        float ai =  cg * sbsa - sg * cbca;
        float br = -(cg * sbca + sg * cbsa);
        float bi =  sg * sbca - cg * cbsa;
        coef[tid] = make_float4(ar, ai, br, bi);
    }

    f2 s[AMPS];
#pragma unroll
    for (int r = 0; r < AMPS; ++r) { s[r].x = 0.f; s[r].y = 0.f; }
    if (tid == 0) s[0].x = 1.f;

    // CZ-ring sign bits (16 per lane)
    unsigned czm = 0;
#pragma unroll
    for (int r = 0; r < AMPS; ++r) {
        unsigned idx  = ((unsigned)wv << 10) | ((unsigned)lane << 4) | (unsigned)r;
        unsigned adj  = (idx & (idx >> 1)) & 0x7FFu;
        unsigned wrap = (idx & (idx >> 11)) & 1u;
        czm |= (((unsigned)__popc(adj) + wrap) & 1u) << r;
    }

    // per-thread wire-bit sign masks / selects (constant through the loop)
    const unsigned sw1 = (unsigned)((wv >> 1) & 1) << 31;   // qubit 0
    const unsigned sw0 = (unsigned)(wv & 1) << 31;          // qubit 1
    const bool hb2 = (lane >> 5) & 1;                       // qubit 2 (xor32)
    const bool hb3 = (lane >> 4) & 1;                       // qubit 3 (xor16)
    const unsigned sb4 = (unsigned)((lane >> 3) & 1) << 31; // qubit 4 (xor8)
    const unsigned sb5 = (unsigned)((lane >> 2) & 1) << 31; // qubit 5 (xor4)
    const unsigned sb6 = (unsigned)((lane >> 1) & 1) << 31; // qubit 6 (xor2)
    const unsigned sb7 = (unsigned)(lane & 1) << 31;        // qubit 7 (xor1)

    const int t64  = tid ^ 64;
    const int t128 = tid ^ 128;
    const int t192 = tid ^ 192;

    __syncthreads();   // coef table ready

#pragma unroll 1
    for (int it = 0; it < NIT; ++it) {
        // ---- load this iteration's 12 matrices (broadcast b128 reads) ----
        float4 c[NQ];
#pragma unroll
        for (int q = 0; q < NQ; ++q) c[q] = coef[it * NQ + q];

        // ---- fused 2-qubit gate on wave wires (qubits 0,1) ----
        {
            const f2 A0 = { c[0].x, f_u(u_f(c[0].y) ^ sw1) };
            const f2 B0 = { f_u(u_f(c[0].z) ^ sw1), c[0].w };
            const f2 A1 = { c[1].x, f_u(u_f(c[1].y) ^ sw0) };
            const f2 B1 = { f_u(u_f(c[1].z) ^ sw0), c[1].w };
            f2 Cs, C64, C128, C192;
            CMUL(Cs,   A0, A1)
            CMUL(C64,  A0, B1)
            CMUL(C128, B0, A1)
            CMUL(C192, B0, B1)

            __syncthreads();   // xch free (all prior readers done)
#pragma unroll
            for (int k = 0; k < 8; ++k)
                xch[(k << 8) + tid] = make_float4(s[2*k].x, s[2*k].y, s[2*k+1].x, s[2*k+1].y);
            __syncthreads();
#pragma unroll
            for (int k = 0; k < 8; ++k) {
                const float4 p1 = xch[(k << 8) + t64];
                const float4 p2 = xch[(k << 8) + t128];
                const float4 p3 = xch[(k << 8) + t192];
                {
                    const f2 o1 = { p1.x, p1.y }, o2 = { p2.x, p2.y }, o3 = { p3.x, p3.y };
                    f2 t0;
                    PK_MUL_RR(t0, Cs, s[2*k]); PK_FMA_I(t0, Cs, s[2*k]);
                    PK_FMA_R(t0, C64,  o1);    PK_FMA_I(t0, C64,  o1);
                    PK_FMA_R(t0, C128, o2);    PK_FMA_I(t0, C128, o2);
                    PK_FMA_R(t0, C192, o3);    PK_FMA_I(t0, C192, o3);
                    s[2*k] = t0;
                }
                {
                    const f2 o1 = { p1.z, p1.w }, o2 = { p2.z, p2.w }, o3 = { p3.z, p3.w };
                    f2 t1;
                    PK_MUL_RR(t1, Cs, s[2*k+1]); PK_FMA_I(t1, Cs, s[2*k+1]);
                    PK_FMA_R(t1, C64,  o1);      PK_FMA_I(t1, C64,  o1);
                    PK_FMA_R(t1, C128, o2);      PK_FMA_I(t1, C128, o2);
                    PK_FMA_R(t1, C192, o3);      PK_FMA_I(t1, C192, o3);
                    s[2*k+1] = t1;
                }
            }
        }

        // ---- register wires (qubits 8..11) ----
        { const f2 CA = { c[8].x,  c[8].y  }, CB = { c[8].z,  c[8].w  }; reg_gate_pk<8>(s, CA, CB); }
        { const f2 CA = { c[9].x,  c[9].y  }, CB = { c[9].z,  c[9].w  }; reg_gate_pk<4>(s, CA, CB); }
        { const f2 CA = { c[10].x, c[10].y }, CB = { c[10].z, c[10].w }; reg_gate_pk<2>(s, CA, CB); }
        { const f2 CA = { c[11].x, c[11].y }, CB = { c[11].z, c[11].w }; reg_gate_pk<1>(s, CA, CB); }

        // ---- lane wires (qubits 2..7) ----
        { // qubit 2: xor32 -> permlane32_swap
            const f2 CP = { hb2 ? -c[2].z : c[2].x, hb2 ?  c[2].w : c[2].y };
            const f2 CQ = { hb2 ?  c[2].x : c[2].z, hb2 ? -c[2].y : c[2].w };
#pragma unroll
            for (int r = 0; r < AMPS; ++r) {
                auto dx = __builtin_amdgcn_permlane32_swap(u_f(s[r].x), u_f(s[r].x), false, false);
                auto dy = __builtin_amdgcn_permlane32_swap(u_f(s[r].y), u_f(s[r].y), false, false);
                f2 na = { f_u(dx[0]), f_u(dy[0]) };
                f2 nb = { f_u(dx[1]), f_u(dy[1]) };
                CPLX_AB(s[r], CP, na, CQ, nb)
            }
        }
        { // qubit 3: xor16 -> permlane16_swap
            const f2 CP = { hb3 ? -c[3].z : c[3].x, hb3 ?  c[3].w : c[3].y };
            const f2 CQ = { hb3 ?  c[3].x : c[3].z, hb3 ? -c[3].y : c[3].w };
#pragma unroll
            for (int r = 0; r < AMPS; ++r) {
                auto dx = __builtin_amdgcn_permlane16_swap(u_f(s[r].x), u_f(s[r].x), false, false);
                auto dy = __builtin_amdgcn_permlane16_swap(u_f(s[r].y), u_f(s[r].y), false, false);
                f2 na = { f_u(dx[0]), f_u(dy[0]) };
                f2 nb = { f_u(dx[1]), f_u(dy[1]) };
                CPLX_AB(s[r], CP, na, CQ, nb)
            }
        }
        { // qubit 4: xor8 -> DPP row_ror:8
            const f2 CA = { c[4].x, f_u(u_f(c[4].y) ^ sb4) };
            const f2 CB = { f_u(u_f(c[4].z) ^ sb4), c[4].w };
            AB_GATE_PK(dpp_xor<0x128>)
        }
        { // qubit 5: xor4 -> ds_swizzle, batched gathers (hide lgkm latency)
            const f2 CA = { c[5].x, f_u(u_f(c[5].y) ^ sb5) };
            const f2 CB = { f_u(u_f(c[5].z) ^ sb5), c[5].w };
#pragma unroll
            for (int h = 0; h < 2; ++h) {
                float ox[8], oy[8];
#pragma unroll
                for (int r = 0; r < 8; ++r) {
                    ox[r] = swz_xor4(s[h*8 + r].x);
                    oy[r] = swz_xor4(s[h*8 + r].y);
                }
#pragma unroll
                for (int r = 0; r < 8; ++r) {
                    f2 o = { ox[r], oy[r] };
                    CPLX_AB(s[h*8 + r], CA, s[h*8 + r], CB, o)
                }
            }
        }
        { // qubit 6: xor2 -> DPP quad_perm [2,3,0,1]
            const f2 CA = { c[6].x, f_u(u_f(c[6].y) ^ sb6) };
            const f2 CB = { f_u(u_f(c[6].z) ^ sb6), c[6].w };
            AB_GATE_PK(dpp_xor<0x4E>)
        }
        { // qubit 7: xor1 -> DPP quad_perm [1,0,3,2]
            const f2 CA = { c[7].x, f_u(u_f(c[7].y) ^ sb7) };
            const f2 CB = { f_u(u_f(c[7].z) ^ sb7), c[7].w };
            AB_GATE_PK(dpp_xor<0xB1>)
        }

        // ---- CZ ring (diagonal +-1) ----
#pragma unroll
        for (int r = 0; r < AMPS; ++r) {
            const unsigned sgn = ((czm >> r) & 1u) << 31;
            s[r].x = f_u(u_f(s[r].x) ^ sgn);
            s[r].y = f_u(u_f(s[r].y) ^ sgn);
        }
    }

    // ---- expvals: Z wires 0..3 -> wv bits 1,0 and lane bits 5,4 ----
    float p = 0.f;
#pragma unroll
    for (int r = 0; r < AMPS; ++r) p = fmaf(s[r].x, s[r].x, fmaf(s[r].y, s[r].y, p));

    float v0 = ((wv   >> 1) & 1) ? -p : p;
    float v1 = ( wv         & 1) ? -p : p;
    float v2 = ((lane >> 5) & 1) ? -p : p;
    float v3 = ((lane >> 4) & 1) ? -p : p;
#pragma unroll
    for (int m = 1; m <= 32; m <<= 1) {
        v0 += __shfl_xor(v0, m);
        v1 += __shfl_xor(v1, m);
        v2 += __shfl_xor(v2, m);
        v3 += __shfl_xor(v3, m);
    }

    __syncthreads();   // LDS reuse for reduction
    if (lane == 0) xch[wv] = make_float4(v0, v1, v2, v3);
    __syncthreads();
    if (tid == 0) {
        float4 a0 = xch[0], a1 = xch[1], a2 = xch[2], a3 = xch[3];
        float4 o;
        o.x = (a0.x + a1.x + a2.x + a3.x) * oscale[0];
        o.y = (a0.y + a1.y + a2.y + a3.y) * oscale[1];
        o.z = (a0.z + a1.z + a2.z + a3.z) * oscale[2];
        o.w = (a0.w + a1.w + a2.w + a3.w) * oscale[3];
        *reinterpret_cast<float4*>(out + (size_t)b * 4) = o;
    }
}

extern "C" void kernel_launch(void* const* d_in, const int* in_sizes, int n_in,
                              void* d_out, int out_size, void* d_ws, size_t ws_size,
                              hipStream_t stream) {
    const float* x      = (const float*)d_in[0];
    const float* iscale = (const float*)d_in[1];
    const float* w      = (const float*)d_in[2];
    const float* oscale = (const float*)d_in[3];
    float* out          = (float*)d_out;

    const int batch = in_sizes[0] / (4 * NQ);
    qsim_kernel<<<batch, 256, 0, stream>>>(x, iscale, w, oscale, out, batch);
}